// Round 11
// baseline (2935.372 us; speedup 1.0000x reference)
//
#include <hip/hip_runtime.h>
#include <cstdint>
#include <cstddef>

// CCDecoder: 16-step input-feeding LSTM + Luong attention decoder.
// B=256, S=512, T=16, H=1024, E=512.
// R11: ONE kernel per step (19 graph nodes total, was 68). R10 analysis:
//   ~20us per serial node boundary dominated (~1300us). Intra-step deps
//   (gates -> W_in -> attn -> W_out) now resolved by per-block FLAGS:
//   producer: syncthreads + release-store (agent scope, no RMW);
//   consumer: relaxed poll (capped ~16ms -> fail visibly, never hang) +
//   one acquire + syncthreads. No RMW contention (R6's 50us gbar was 256
//   serialized fetch_adds). Deadlock-free: 256 blocks x 256thr = 1/CU all
//   co-resident; producer phases precede consumer phases in program order;
//   flag graph acyclic per m-tile (gflag -> tflag -> aflag).
//   GEMM re-tiled for 256 thr: 4 waves (2x2), 32x32 acc/wave, NBUF=4,
//   2-deep prefetch, counted vmcnt(8/4/0) (4 loads/thread/stage).
//   Final h,c written directly by t==15 gates epilogue (no memcpy nodes).

#define B_ 256
#define S_ 512
#define T_ 16
#define H_ 1024
#define E_ 512
#define NBUF 4

typedef unsigned short u16;
using short8 = __attribute__((ext_vector_type(8))) short;
using f32x4  = __attribute__((ext_vector_type(4))) float;

__device__ __forceinline__ float bf2f(u16 u) {
  union { uint32_t i; float f; } v; v.i = ((uint32_t)u) << 16; return v.f;
}
__device__ __forceinline__ u16 f2bf(float f) {
  union { uint32_t i; float f; } v; v.f = f;
  uint32_t r = v.i + 0x7fffu + ((v.i >> 16) & 1u);
  return (u16)(r >> 16);
}
__device__ __forceinline__ ushort4 cvt4bf(float4 v) {
  ushort4 o; o.x = f2bf(v.x); o.y = f2bf(v.y); o.z = f2bf(v.z); o.w = f2bf(v.w);
  return o;
}
__device__ __forceinline__ float sigmoidf_(float x) { return 1.f / (1.f + __expf(-x)); }

__device__ __forceinline__ void gload_lds16(const void* g, void* l) {
  __builtin_amdgcn_global_load_lds(
      (const __attribute__((address_space(1))) void*)g,
      (__attribute__((address_space(3))) void*)l, 16, 0, 0);
}

// ---- flag protocol (contention-free producer/consumer sync) ----
__device__ __forceinline__ void st_flag(int* p) {
  __hip_atomic_store(p, 1, __ATOMIC_RELEASE, __HIP_MEMORY_SCOPE_AGENT);
}
__device__ __forceinline__ void wait_flags(int* f, int nf, int tid) {
  if (tid < nf) {
    unsigned cnt = 0;
    while (__hip_atomic_load(f + tid, __ATOMIC_RELAXED, __HIP_MEMORY_SCOPE_AGENT) == 0 &&
           cnt < (1u << 18)) {   // cap: fail visibly instead of hanging
      __builtin_amdgcn_s_sleep(2);
      ++cnt;
    }
    int v = __hip_atomic_load(f + tid, __ATOMIC_ACQUIRE, __HIP_MEMORY_SCOPE_AGENT);
    asm volatile("" :: "v"(v) : "memory");
  }
  __syncthreads();
}

struct Reg3 { const u16* A; int lda; const u16* B; int ldb; int kt; };

union SMem {
  struct { u16 A[NBUF][4096]; u16 B[NBUF][4096]; } g;            // 64 KB
  struct { float facc[2][1024]; float fm[4], fl[4]; } a;         // 8.03 KB
};

// ---------------------------------------------------------------- GEMM (4-wave)
// 64x64 output tile, 256 thr = 4 waves (2x2), 32x32 acc/wave (acc[2][2]).
// Per k-iter per wave: 8 ds_read_b128 + 8 MFMA. NBUF=4, 2-deep prefetch
// (stage(ti+2)&3 vs laggard reads (ti-1)&3 never collide), counted
// vmcnt(8/4/0) (4 uniform loads/thread/stage). XOR swizzle both sides.
template <int EPI>   // 1: bf16->Cb  2: tanh->fp32 out+bf16 Cb  3: fused LSTM
__device__ void gemm4(SMem* sm, const int tid, const int m0, const int n0,
                      const Reg3 r0, const Reg3 r1, const Reg3 r2,
                      float* __restrict__ Cf, u16* __restrict__ Cb,
                      const float* __restrict__ bsum, float* __restrict__ cst,
                      u16* __restrict__ hbfo, float* __restrict__ outHC,
                      const int tstep) {
  const int lane = tid & 63;
  const int wave = tid >> 6;
  const int wm = wave >> 1, wn = wave & 1;
  const int row16 = lane & 15;
  const int kg = lane >> 4;
  const int nt = r0.kt + r1.kt + r2.kt;

  auto stage = [&](int ti, int buf) {
    const int k01 = r0.kt + r1.kt;
    const u16* Ap = (ti < r0.kt) ? r0.A : (ti < k01) ? r1.A : r2.A;
    const u16* Bp = (ti < r0.kt) ? r0.B : (ti < k01) ? r1.B : r2.B;
    const int lda = (ti < r0.kt) ? r0.lda : (ti < k01) ? r1.lda : r2.lda;
    const int ldb = (ti < r0.kt) ? r0.ldb : (ti < k01) ? r1.ldb : r2.ldb;
    const int base = (ti < r0.kt) ? 0 : (ti < k01) ? r0.kt : k01;
    const int kr = (ti - base) << 6;
#pragma unroll
    for (int j = 0; j < 2; ++j) {   // A: 64x64 = 512 chunks, 2/thread
      const int c = j * 256 + tid;
      const int row = c >> 3, q = c & 7;
      gload_lds16(Ap + (size_t)(m0 + row) * lda + kr + ((q ^ (row & 7)) << 3),
                  (char*)&sm->g.A[buf][0] + (size_t)(j * 256 + wave * 64) * 16);
    }
#pragma unroll
    for (int j = 0; j < 2; ++j) {   // B: 64x64 = 512 chunks, 2/thread
      const int c = j * 256 + tid;
      const int row = c >> 3, q = c & 7;
      gload_lds16(Bp + (size_t)(n0 + row) * ldb + kr + ((q ^ (row & 7)) << 3),
                  (char*)&sm->g.B[buf][0] + (size_t)(j * 256 + wave * 64) * 16);
    }
  };

  f32x4 acc[2][2] = {};
  stage(0, 0);
  if (nt > 1) stage(1, 1);
  for (int ti = 0; ti < nt; ++ti) {
    const int buf = ti & 3;
    if (ti + 2 < nt) {
      stage(ti + 2, (ti + 2) & 3);
      asm volatile("s_waitcnt vmcnt(8)" ::: "memory");
    } else if (ti + 1 < nt) {
      asm volatile("s_waitcnt vmcnt(4)" ::: "memory");
    } else {
      asm volatile("s_waitcnt vmcnt(0)" ::: "memory");
    }
    __builtin_amdgcn_s_barrier();
    __builtin_amdgcn_sched_barrier(0);
#pragma unroll
    for (int ks = 0; ks < 2; ++ks) {
      short8 af[2], bfr[2];
#pragma unroll
      for (int mi = 0; mi < 2; ++mi) {
        const int R = wm * 32 + mi * 16 + row16;
        af[mi] = *(const short8*)((const char*)&sm->g.A[buf][0] +
                                  (size_t)(((R << 3) | ((ks * 4 + kg) ^ (R & 7))) << 4));
      }
#pragma unroll
      for (int ni = 0; ni < 2; ++ni) {
        const int R = wn * 32 + ni * 16 + row16;
        bfr[ni] = *(const short8*)((const char*)&sm->g.B[buf][0] +
                                   (size_t)(((R << 3) | ((ks * 4 + kg) ^ (R & 7))) << 4));
      }
      asm volatile("s_waitcnt lgkmcnt(0)" ::: "memory");
      __builtin_amdgcn_sched_barrier(0);
#pragma unroll
      for (int mi = 0; mi < 2; ++mi)
#pragma unroll
        for (int ni = 0; ni < 2; ++ni)
          acc[mi][ni] = __builtin_amdgcn_mfma_f32_16x16x32_bf16(af[mi], bfr[ni], acc[mi][ni], 0, 0, 0);
      __builtin_amdgcn_sched_barrier(0);
    }
  }
  __builtin_amdgcn_s_barrier();   // LDS safe for next phase (R6 lesson)
  // C/D layout: col = lane&15, row = (lane>>4)*4 + r  [m89-verified]
#pragma unroll
  for (int mi = 0; mi < 2; ++mi) {
#pragma unroll
    for (int ni = 0; ni < 2; ++ni) {
#pragma unroll
      for (int r = 0; r < 4; ++r) {
        const int row = m0 + wm * 32 + mi * 16 + (kg << 2) + r;
        const int col = n0 + wn * 32 + ni * 16 + row16;
        float v = acc[mi][ni][r];
        if (EPI == 1) {
          Cb[row * H_ + col] = f2bf(v);
        } else if (EPI == 2) {
          float tv = tanhf(v);
          Cf[(size_t)row * (T_ * H_) + (size_t)tstep * H_ + col] = tv;
          Cb[row * H_ + col] = f2bf(tv);
        } else {
          // gate-interleaved: col&3 = gate(i,f,g,o), col>>2 = unit
          v += bsum[col];
          float v1 = __shfl_xor(v, 1);
          float v2 = __shfl_xor(v, 2);
          float v3 = __shfl_xor(v, 3);
          if ((lane & 3) == 0) {
            const int u = col >> 2;
            float iv = sigmoidf_(v);
            float fv = sigmoidf_(v1);
            float gv = tanhf(v2);
            float ov = sigmoidf_(v3);
            float cn = fv * cst[row * H_ + u] + iv * gv;
            float hn = ov * tanhf(cn);
            cst[row * H_ + u] = cn;
            hbfo[row * H_ + u] = f2bf(hn);
            if (outHC) {                       // t==15: final h,c directly
              outHC[row * H_ + u] = hn;
              outHC[B_ * H_ + row * H_ + u] = cn;
            }
          }
        }
      }
    }
  }
}

// ---------------------------------------------------------------- attention (4-wave)
__device__ __forceinline__ int fidx(int lane, int j) {
  return (j << 6) + ((lane + (j << 2)) & 63);
}

__device__ void attn4(SMem* sm, const int bid, const int tid,
                      const u16* __restrict__ tgt, const u16* __restrict__ ctxc,
                      const int* __restrict__ woffs, const int* __restrict__ src_len,
                      u16* __restrict__ wwbf) {
  const int lane = tid & 63;
  const int wave = tid >> 6;
  const int len = src_len[bid];
  const u16* cb = ctxc + ((size_t)woffs[bid] << 10);

  float tg[16];
  {
    const u16* tp = tgt + bid * H_ + lane * 16;
    short8 v1 = *(const short8*)tp;
    short8 v2 = *(const short8*)(tp + 8);
#pragma unroll
    for (int j = 0; j < 8; ++j) { tg[j] = bf2f((u16)v1[j]); tg[8 + j] = bf2f((u16)v2[j]); }
  }
  float m = -1e30f, l = 0.f;
  float acc[16];
#pragma unroll
  for (int j = 0; j < 16; ++j) acc[j] = 0.f;

  for (int s = wave; s < len; s += 4) {
    const u16* cr = cb + ((size_t)s << 10) + (lane << 4);
    short8 v1 = *(const short8*)cr;
    short8 v2 = *(const short8*)(cr + 8);
    float cf[16];
#pragma unroll
    for (int j = 0; j < 8; ++j) { cf[j] = bf2f((u16)v1[j]); cf[8 + j] = bf2f((u16)v2[j]); }
    float x = 0.f;
#pragma unroll
    for (int j = 0; j < 16; ++j) x += cf[j] * tg[j];
#pragma unroll
    for (int off = 1; off < 64; off <<= 1) x += __shfl_xor(x, off);
    if (x > m) {                      // wave-uniform after reduce
      float sc_ = __expf(m - x);
      l *= sc_;
#pragma unroll
      for (int j = 0; j < 16; ++j) acc[j] *= sc_;
      m = x;
    }
    float p = __expf(x - m);
    l += p;
#pragma unroll
    for (int j = 0; j < 16; ++j) acc[j] += p * cf[j];
  }

  if (wave >= 2) {
#pragma unroll
    for (int j = 0; j < 16; ++j) sm->a.facc[wave - 2][fidx(lane, j)] = acc[j];
    if (lane == 0) { sm->a.fm[wave] = m; sm->a.fl[wave] = l; }
  }
  __syncthreads();
  if (wave < 2) {
    float pm = sm->a.fm[wave + 2];
    float pl = sm->a.fl[wave + 2];
    float M = fmaxf(m, pm);
    float e1 = __expf(m - M);
    float e2 = __expf(pm - M);
#pragma unroll
    for (int j = 0; j < 16; ++j) {
      float pv = sm->a.facc[wave][fidx(lane, j)];
      sm->a.facc[wave][fidx(lane, j)] = acc[j] * e1 + pv * e2;
    }
    if (lane == 0) { sm->a.fm[wave] = M; sm->a.fl[wave] = l * e1 + pl * e2; }
  }
  __syncthreads();
  const float m0v = sm->a.fm[0], m1v = sm->a.fm[1];
  const float ms = fmaxf(m0v, m1v);
  const float e0 = __expf(m0v - ms), e1 = __expf(m1v - ms);
  const float inv = 1.f / (sm->a.fl[0] * e0 + sm->a.fl[1] * e1);
  ushort4 o;
#pragma unroll
  for (int jj = 0; jj < 4; ++jj) {
    const int c = tid * 4 + jj;
    const int ri = fidx(c >> 4, c & 15);
    float a = sm->a.facc[0][ri] * e0 + sm->a.facc[1][ri] * e1;
    ((u16*)&o)[jj] = f2bf(a * inv);
  }
  *(ushort4*)(wwbf + bid * H_ + tid * 4) = o;
}

// ---------------------------------------------------------------- step kernel
struct SP {
  const u16 *wemb, *wWih, *wWhh, *wWin, *wWout;
  const float* bsum;
  float* wc;
  const u16* hcur;
  u16 *hnxt, *whtbf, *wtgt, *wwbf;
  const u16* ctxc;
  const int *woffs, *src_len;
  float* out;
  int *gflag, *tflag, *aflag;
  int t;
};

__global__ __launch_bounds__(256) void step_k(SP P) {
  __shared__ SMem sm;
  const int tid = threadIdx.x;
  const int bid = blockIdx.x;
  const int m = bid & 3;
  const int n = bid >> 2;
  Reg3 rz = { nullptr, 0, nullptr, 0, 0 };

  {  // gates + fused LSTM  (M=256, N=4096 gi, K=512+1024+1024) - all 256 blocks
    Reg3 g0 = { P.wemb + (size_t)P.t * E_, T_ * E_, P.wWih,      E_ + H_, 8 };
    Reg3 g1 = { P.whtbf,                   H_,      P.wWih + E_, E_ + H_, 16 };
    Reg3 g2 = { P.hcur,                    H_,      P.wWhh,      H_,      16 };
    gemm4<3>(&sm, tid, m * 64, n * 64, g0, g1, g2, nullptr, nullptr,
             P.bsum, P.wc, P.hnxt,
             (P.t == T_ - 1) ? P.out + (size_t)B_ * T_ * H_ : nullptr, 0);
    __syncthreads();
    if (tid == 0) st_flag(P.gflag + m * 64 + n);
  }
  if (bid < 64) {  // target = h @ W_in^T  (M=256, N=1024, K=1024)
    wait_flags(P.gflag + m * 64, 64, tid);          // h m-tile complete
    Reg3 i0 = { P.hnxt, H_, P.wWin, H_, 16 };
    gemm4<1>(&sm, tid, m * 64, n * 64, i0, rz, rz, nullptr, P.wtgt,
             nullptr, nullptr, nullptr, nullptr, 0);
    __syncthreads();
    if (tid == 0) st_flag(P.tflag + m * 16 + n);
  }
  // attention row `bid` (all 256 blocks)
  wait_flags(P.tflag + (bid >> 6) * 16, 16, tid);   // target m-tile complete
  attn4(&sm, bid, tid, P.wtgt, P.ctxc, P.woffs, P.src_len, P.wwbf);
  __syncthreads();
  if (tid == 0) st_flag(P.aflag + (bid >> 6) * 64 + (bid & 63));
  if (bid < 64) {  // htilde = tanh([weighted|h] @ W_out^T) -> out + whtbf
    wait_flags(P.aflag + m * 64, 64, tid);          // weighted m-tile complete
    Reg3 o0 = { P.wwbf, H_, P.wWout,      2 * H_, 16 };
    Reg3 o1 = { P.hnxt, H_, P.wWout + H_, 2 * H_, 16 };
    gemm4<2>(&sm, tid, m * 64, n * 64, o0, o1, rz, P.out, P.whtbf,
             nullptr, nullptr, nullptr, nullptr, P.t);
  }
}

// ---------------------------------------------------------------- compaction
// Block b: compute its own exclusive offset (sum len[0..b)) + copy rows.
__global__ __launch_bounds__(256) void ctx_compact(const float* __restrict__ ctx,
                                                   const int* __restrict__ src_len,
                                                   int* __restrict__ woffs,
                                                   u16* __restrict__ ctxc) {
  __shared__ int tmp[256];
  const int b = blockIdx.x;
  const int tid = threadIdx.x;
  tmp[tid] = (tid < b) ? src_len[tid] : 0;
  __syncthreads();
  for (int o = 128; o > 0; o >>= 1) {
    if (tid < o) tmp[tid] += tmp[tid + o];
    __syncthreads();
  }
  const int off = tmp[0];
  if (tid == 0) woffs[b] = off;
  const int n4 = src_len[b] << 8;     // len*1024/4 vec4s
  const float4* s = (const float4*)(ctx + ((size_t)b << 19));
  ushort4* d = (ushort4*)(ctxc + ((size_t)off << 10));
  for (int i = tid; i < n4; i += 256) d[i] = cvt4bf(s[i]);
}

// ---------------------------------------------------------------- converts
__global__ __launch_bounds__(256) void convert_all(
    const float* __restrict__ W_ih, const float* __restrict__ W_hh,
    const float* __restrict__ W_in, const float* __restrict__ W_out,
    const float* __restrict__ trg_emb,
    const float* __restrict__ b_ih, const float* __restrict__ b_hh,
    const float* __restrict__ h0, const float* __restrict__ c0,
    u16* __restrict__ wWih, u16* __restrict__ wWhh, u16* __restrict__ wWin,
    u16* __restrict__ wWout, u16* __restrict__ wemb,
    float* __restrict__ wbsum, u16* __restrict__ wh0, u16* __restrict__ whtbf,
    float* __restrict__ wc) {
  const int gtid = blockIdx.x * 256 + threadIdx.x;
  const int GSZ = 1024 * 256;
  for (int i = gtid; i < 1572864; i += GSZ) {     // W_ih gi (4096x1536)
    const int r = i / 384, c4 = i - r * 384;
    const int rp = ((r & 1023) << 2) + (r >> 10);
    ((ushort4*)wWih)[(size_t)rp * 384 + c4] = cvt4bf(((const float4*)W_ih)[i]);
  }
  for (int i = gtid; i < 1048576; i += GSZ) {     // W_hh gi (4096x1024)
    const int r = i >> 8, c4 = i & 255;
    const int rp = ((r & 1023) << 2) + (r >> 10);
    ((ushort4*)wWhh)[(size_t)rp * 256 + c4] = cvt4bf(((const float4*)W_hh)[i]);
  }
  for (int i = gtid; i < 262144; i += GSZ)        // W_in (1024x1024)
    ((ushort4*)wWin)[i] = cvt4bf(((const float4*)W_in)[i]);
  for (int i = gtid; i < 524288; i += GSZ)        // W_out (1024x2048)
    ((ushort4*)wWout)[i] = cvt4bf(((const float4*)W_out)[i]);
  for (int i = gtid; i < 524288; i += GSZ)        // emb (B,T,E)
    ((ushort4*)wemb)[i] = cvt4bf(((const float4*)trg_emb)[i]);
  if (gtid < 4096) {                              // bias (gi)
    const int cp = ((gtid & 1023) << 2) + (gtid >> 10);
    wbsum[cp] = b_ih[gtid] + b_hh[gtid];
  }
  for (int i = gtid; i < 262144; i += GSZ) {      // state init
    u16 hb = f2bf(h0[i]);
    wh0[i] = hb;
    whtbf[i] = hb;
    wc[i] = c0[i];
  }
}

// ---------------------------------------------------------------- host
extern "C" void kernel_launch(void* const* d_in, const int* in_sizes, int n_in,
                              void* d_out, int out_size, void* d_ws, size_t ws_size,
                              hipStream_t stream) {
  const float* trg_emb = (const float*)d_in[0];
  const float* h0      = (const float*)d_in[1];
  const float* c0      = (const float*)d_in[2];
  const float* ctx     = (const float*)d_in[3];
  const int*   src_len = (const int*)d_in[4];
  const float* W_ih    = (const float*)d_in[5];
  const float* W_hh    = (const float*)d_in[6];
  const float* b_ih    = (const float*)d_in[7];
  const float* b_hh    = (const float*)d_in[8];
  const float* W_in    = (const float*)d_in[9];
  const float* W_out   = (const float*)d_in[10];
  float* out = (float*)d_out;

  char* w = (char*)d_ws;
  size_t off = 0;
  auto alloc = [&](size_t bytes) { char* p = w + off; off += bytes; return p; };
  u16*   wWih  = (u16*)  alloc(12582912);   // 4096x1536 bf16 (gi rows)
  u16*   wWhh  = (u16*)  alloc(8388608);    // 4096x1024 bf16 (gi rows)
  u16*   wWin  = (u16*)  alloc(2097152);    // 1024x1024
  u16*   wWout = (u16*)  alloc(4194304);    // 1024x2048
  u16*   wemb  = (u16*)  alloc(4194304);    // (B,T,E) bf16
  float* wbsum = (float*)alloc(16384);
  float* wc    = (float*)alloc(1048576);
  u16*   wh0   = (u16*)  alloc(524288);     // h ping
  u16*   wh1   = (u16*)  alloc(524288);     // h pong
  u16*   whtbf = (u16*)  alloc(524288);
  u16*   wtgt  = (u16*)  alloc(524288);
  u16*   wwbf  = (u16*)  alloc(524288);
  int*   woffs = (int*)  alloc(1024);
  int*   flags = (int*)  alloc(36864);      // 16*(256+64+256) ints
  u16*   wctxc = (u16*)  alloc(268435456);  // compacted ctx bf16 (worst case)
  (void)ws_size;
  int* gflagA = flags;                 // [16][4][64]
  int* tflagA = flags + 16 * 256;      // [16][4][16]
  int* aflagA = flags + 16 * 256 + 16 * 64;  // [16][4][64]

  hipMemsetAsync(flags, 0, 36864, stream);
  convert_all<<<dim3(1024), dim3(256), 0, stream>>>(
      W_ih, W_hh, W_in, W_out, trg_emb, b_ih, b_hh, h0, c0,
      wWih, wWhh, wWin, wWout, wemb, wbsum, wh0, whtbf, wc);
  ctx_compact<<<dim3(B_), dim3(256), 0, stream>>>(ctx, src_len, woffs, wctxc);

  for (int t = 0; t < T_; ++t) {
    SP P;
    P.wemb = wemb; P.wWih = wWih; P.wWhh = wWhh; P.wWin = wWin; P.wWout = wWout;
    P.bsum = wbsum; P.wc = wc;
    P.hcur = (t & 1) ? wh1 : wh0;
    P.hnxt = (t & 1) ? wh0 : wh1;
    P.whtbf = whtbf; P.wtgt = wtgt; P.wwbf = wwbf;
    P.ctxc = wctxc; P.woffs = woffs; P.src_len = src_len;
    P.out = out;
    P.gflag = gflagA + t * 256;
    P.tflag = tflagA + t * 64;
    P.aflag = aflagA + t * 256;
    P.t = t;
    step_k<<<dim3(B_), dim3(256), 0, stream>>>(P);
  }
}

// Round 12
// 1914.229 us; speedup vs baseline: 1.5334x; 1.5334x over previous
//
#include <hip/hip_runtime.h>
#include <cstdint>
#include <cstddef>

// CCDecoder: 16-step input-feeding LSTM + Luong attention decoder.
// B=256, S=512, T=16, H=1024, E=512.
// R12 = R10 structure (multi-launch; grid-wide sync refuted at 35-50us by
//   R4/R6/R11) with:
//   - GEMM: 4-wave 256-thr blocks (R11-proven inner loop), NBUF=6, 4-deep
//     prefetch, vmcnt(16/12/8/4/0). Safety proof: stage(k) issues between
//     barrier(k-5) and barrier(k-4); concurrent readers j in {k-5,k-4};
//     buffer distance 5,4 mod 6 != 0. (R7's depth3/NBUF4 violated this.)
//   - attn: 512 blocks x 512 thr; block pair (2p,2p+1) = halves of row p.
//     Odd writes partial + release flag; even polls (capped) THEN FALLS BACK
//     to computing the odd half itself -> deadlock-impossible, co-residency
//     is an optimization only (G16-safe). Balances the len tail.
//   - final h,c from t==15 gates epilogue (-2 memcpy nodes); compact merged
//     into convert (-1 node); flags zeroed by one memset node.

#define B_ 256
#define S_ 512
#define T_ 16
#define H_ 1024
#define E_ 512
#define NBUF 6

typedef unsigned short u16;
using short8 = __attribute__((ext_vector_type(8))) short;
using f32x4  = __attribute__((ext_vector_type(4))) float;

__device__ __forceinline__ float bf2f(u16 u) {
  union { uint32_t i; float f; } v; v.i = ((uint32_t)u) << 16; return v.f;
}
__device__ __forceinline__ u16 f2bf(float f) {
  union { uint32_t i; float f; } v; v.f = f;
  uint32_t r = v.i + 0x7fffu + ((v.i >> 16) & 1u);
  return (u16)(r >> 16);
}
__device__ __forceinline__ ushort4 cvt4bf(float4 v) {
  ushort4 o; o.x = f2bf(v.x); o.y = f2bf(v.y); o.z = f2bf(v.z); o.w = f2bf(v.w);
  return o;
}
__device__ __forceinline__ float sigmoidf_(float x) { return 1.f / (1.f + __expf(-x)); }

__device__ __forceinline__ void gload_lds16(const void* g, void* l) {
  __builtin_amdgcn_global_load_lds(
      (const __attribute__((address_space(1))) void*)g,
      (__attribute__((address_space(3))) void*)l, 16, 0, 0);
}

struct Reg3 { const u16* A; int lda; const u16* B; int ldb; int kt; };

// ---------------------------------------------------------------- GEMM
// 64x64 tile, 256 thr = 4 waves (2x2), 32x32 acc/wave (acc[2][2]).
// NBUF=6, 4-deep prefetch, counted vmcnt (4 loads/thread/stage).
// XOR swizzle (chunk ^= row&7) on both global-src and ds_read sides.
template <int EPI>   // 1: bf16->Cb  2: tanh->fp32 out+bf16 Cb  3: fused LSTM
__global__ __launch_bounds__(256) void gemm_k(Reg3 r0, Reg3 r1, Reg3 r2,
                                              int nmb,
                                              float* __restrict__ Cf,
                                              u16* __restrict__ Cb,
                                              const float* __restrict__ bsum,
                                              float* __restrict__ cst,
                                              u16* __restrict__ hbfo,
                                              float* __restrict__ outHC,
                                              const int tstep) {
  __shared__ u16 smA[NBUF][4096];
  __shared__ u16 smB[NBUF][4096];
  const int tid = threadIdx.x;
  const int lane = tid & 63;
  const int wave = tid >> 6;
  const int wm = wave >> 1, wn = wave & 1;
  const int m0 = (blockIdx.x % nmb) * 64;
  const int n0 = (blockIdx.x / nmb) * 64;
  const int row16 = lane & 15;
  const int kg = lane >> 4;
  const int nt = r0.kt + r1.kt + r2.kt;

  auto stage = [&](int ti, int buf) {
    const int k01 = r0.kt + r1.kt;
    const u16* Ap = (ti < r0.kt) ? r0.A : (ti < k01) ? r1.A : r2.A;
    const u16* Bp = (ti < r0.kt) ? r0.B : (ti < k01) ? r1.B : r2.B;
    const int lda = (ti < r0.kt) ? r0.lda : (ti < k01) ? r1.lda : r2.lda;
    const int ldb = (ti < r0.kt) ? r0.ldb : (ti < k01) ? r1.ldb : r2.ldb;
    const int base = (ti < r0.kt) ? 0 : (ti < k01) ? r0.kt : k01;
    const int kr = (ti - base) << 6;
#pragma unroll
    for (int j = 0; j < 2; ++j) {   // A: 64x64 = 512 chunks, 2/thread
      const int c = j * 256 + tid;
      const int row = c >> 3, q = c & 7;
      gload_lds16(Ap + (size_t)(m0 + row) * lda + kr + ((q ^ (row & 7)) << 3),
                  (char*)&smA[buf][0] + (size_t)(j * 256 + wave * 64) * 16);
    }
#pragma unroll
    for (int j = 0; j < 2; ++j) {   // B: 64x64 = 512 chunks, 2/thread
      const int c = j * 256 + tid;
      const int row = c >> 3, q = c & 7;
      gload_lds16(Bp + (size_t)(n0 + row) * ldb + kr + ((q ^ (row & 7)) << 3),
                  (char*)&smB[buf][0] + (size_t)(j * 256 + wave * 64) * 16);
    }
  };

  f32x4 acc[2][2] = {};
  stage(0, 0);
  if (nt > 1) stage(1, 1);
  if (nt > 2) stage(2, 2);
  if (nt > 3) stage(3, 3);
  for (int ti = 0; ti < nt; ++ti) {
    const int buf = ti % NBUF;
    if (ti + 4 < nt) {
      stage(ti + 4, (ti + 4) % NBUF);
      asm volatile("s_waitcnt vmcnt(16)" ::: "memory");
    } else if (ti + 3 < nt) {
      asm volatile("s_waitcnt vmcnt(12)" ::: "memory");
    } else if (ti + 2 < nt) {
      asm volatile("s_waitcnt vmcnt(8)" ::: "memory");
    } else if (ti + 1 < nt) {
      asm volatile("s_waitcnt vmcnt(4)" ::: "memory");
    } else {
      asm volatile("s_waitcnt vmcnt(0)" ::: "memory");
    }
    __builtin_amdgcn_s_barrier();
    __builtin_amdgcn_sched_barrier(0);
#pragma unroll
    for (int ks = 0; ks < 2; ++ks) {
      short8 af[2], bfr[2];
#pragma unroll
      for (int mi = 0; mi < 2; ++mi) {
        const int R = wm * 32 + mi * 16 + row16;
        af[mi] = *(const short8*)((const char*)&smA[buf][0] +
                                  (size_t)(((R << 3) | ((ks * 4 + kg) ^ (R & 7))) << 4));
      }
#pragma unroll
      for (int ni = 0; ni < 2; ++ni) {
        const int R = wn * 32 + ni * 16 + row16;
        bfr[ni] = *(const short8*)((const char*)&smB[buf][0] +
                                   (size_t)(((R << 3) | ((ks * 4 + kg) ^ (R & 7))) << 4));
      }
      asm volatile("s_waitcnt lgkmcnt(0)" ::: "memory");
      __builtin_amdgcn_sched_barrier(0);
#pragma unroll
      for (int mi = 0; mi < 2; ++mi)
#pragma unroll
        for (int ni = 0; ni < 2; ++ni)
          acc[mi][ni] = __builtin_amdgcn_mfma_f32_16x16x32_bf16(af[mi], bfr[ni], acc[mi][ni], 0, 0, 0);
      __builtin_amdgcn_sched_barrier(0);
    }
  }
  // C/D layout: col = lane&15, row = (lane>>4)*4 + r  [m89-verified]
#pragma unroll
  for (int mi = 0; mi < 2; ++mi) {
#pragma unroll
    for (int ni = 0; ni < 2; ++ni) {
#pragma unroll
      for (int r = 0; r < 4; ++r) {
        const int row = m0 + wm * 32 + mi * 16 + (kg << 2) + r;
        const int col = n0 + wn * 32 + ni * 16 + row16;
        float v = acc[mi][ni][r];
        if (EPI == 1) {
          Cb[row * H_ + col] = f2bf(v);
        } else if (EPI == 2) {
          float tv = tanhf(v);
          Cf[(size_t)row * (T_ * H_) + (size_t)tstep * H_ + col] = tv;
          Cb[row * H_ + col] = f2bf(tv);
        } else {
          // gate-interleaved: col&3 = gate(i,f,g,o), col>>2 = unit
          v += bsum[col];
          float v1 = __shfl_xor(v, 1);
          float v2 = __shfl_xor(v, 2);
          float v3 = __shfl_xor(v, 3);
          if ((lane & 3) == 0) {
            const int u = col >> 2;
            float iv = sigmoidf_(v);
            float fv = sigmoidf_(v1);
            float gv = tanhf(v2);
            float ov = sigmoidf_(v3);
            float cn = fv * cst[row * H_ + u] + iv * gv;
            float hn = ov * tanhf(cn);
            cst[row * H_ + u] = cn;
            hbfo[row * H_ + u] = f2bf(hn);
            if (outHC) {                     // t==15: final h,c directly
              outHC[row * H_ + u] = hn;
              outHC[B_ * H_ + row * H_ + u] = cn;
            }
          }
        }
      }
    }
  }
}

// ---------------------------------------------------------------- attention
// 512 blocks x 512 thr (8 waves). Pair (2p, 2p+1) = halves of row p.
// Odd block: partial (m,l,acc) -> ws + release flag. Even block: own half,
// poll (capped ~small) -> merge; on cap expiry FALL BACK to computing the
// odd half itself (correct regardless of scheduling; co-residency is an
// optimization only).
__device__ __forceinline__ int fidx(int lane, int j) {
  return (j << 6) + ((lane + (j << 2)) & 63);
}

__global__ __launch_bounds__(512, 4) void attn_pair(const u16* __restrict__ tgt,
                                                    const u16* __restrict__ ctxc,
                                                    const int* __restrict__ woffs,
                                                    const int* __restrict__ src_len,
                                                    u16* __restrict__ wwbf,
                                                    float* __restrict__ pacc,
                                                    float* __restrict__ pml,
                                                    int* __restrict__ flag) {
  __shared__ float facc[7][1024];
  __shared__ float fm[8], fl[8];
  const int p = blockIdx.x >> 1;
  const int half = blockIdx.x & 1;
  const int tid = threadIdx.x;
  const int lane = tid & 63;
  const int wave = tid >> 6;           // 0..7
  const int len = src_len[p];
  const int len2 = (len + 1) >> 1;
  const u16* cb = ctxc + ((size_t)woffs[p] << 10);

  float tg[16];
  {
    const u16* tp = tgt + p * H_ + lane * 16;
    short8 v1 = *(const short8*)tp;
    short8 v2 = *(const short8*)(tp + 8);
#pragma unroll
    for (int j = 0; j < 8; ++j) { tg[j] = bf2f((u16)v1[j]); tg[8 + j] = bf2f((u16)v2[j]); }
  }
  float m = -1e30f, l = 0.f;
  float acc[16];
#pragma unroll
  for (int j = 0; j < 16; ++j) acc[j] = 0.f;

  auto process = [&](int s) {
    const u16* cr = cb + ((size_t)s << 10) + (lane << 4);
    short8 v1 = *(const short8*)cr;
    short8 v2 = *(const short8*)(cr + 8);
    float cf[16];
#pragma unroll
    for (int j = 0; j < 8; ++j) { cf[j] = bf2f((u16)v1[j]); cf[8 + j] = bf2f((u16)v2[j]); }
    float x = 0.f;
#pragma unroll
    for (int j = 0; j < 16; ++j) x += cf[j] * tg[j];
#pragma unroll
    for (int off = 1; off < 64; off <<= 1) x += __shfl_xor(x, off);
    if (x > m) {                       // wave-uniform after reduce
      float sc_ = __expf(m - x);
      l *= sc_;
#pragma unroll
      for (int j = 0; j < 16; ++j) acc[j] *= sc_;
      m = x;
    }
    float pv = __expf(x - m);
    l += pv;
#pragma unroll
    for (int j = 0; j < 16; ++j) acc[j] += pv * cf[j];
  };

  const int lo = half ? len2 : 0;
  const int hi = half ? len : len2;
  for (int s = lo + wave; s < hi; s += 8) process(s);

  // merge 8 wave-partials into wave 0
  if (wave >= 1) {
#pragma unroll
    for (int j = 0; j < 16; ++j) facc[wave - 1][fidx(lane, j)] = acc[j];
    if (lane == 0) { fm[wave] = m; fl[wave] = l; }
  }
  __syncthreads();
  if (wave == 0) {
#pragma unroll
    for (int w = 1; w < 8; ++w) {
      float pm2 = fm[w], pl2 = fl[w];
      float M = fmaxf(m, pm2);
      float e1 = __expf(m - M), e2 = __expf(pm2 - M);
#pragma unroll
      for (int j = 0; j < 16; ++j)
        acc[j] = acc[j] * e1 + facc[w - 1][fidx(lane, j)] * e2;
      l = l * e1 + pl2 * e2;
      m = M;
    }
    if (half == 1) {                   // producer: publish partial
      float* pa = pacc + (size_t)p * 1024;
#pragma unroll
      for (int j4 = 0; j4 < 4; ++j4) {
        float4 v;
        v.x = acc[j4 * 4]; v.y = acc[j4 * 4 + 1];
        v.z = acc[j4 * 4 + 2]; v.w = acc[j4 * 4 + 3];
        *(float4*)&pa[lane * 16 + j4 * 4] = v;
      }
      if (lane == 0) { pml[2 * p] = m; pml[2 * p + 1] = l; }
      asm volatile("s_waitcnt vmcnt(0)" ::: "memory");
      if (lane == 0)
        __hip_atomic_store(flag + p, 1, __ATOMIC_RELEASE, __HIP_MEMORY_SCOPE_AGENT);
    } else {                           // consumer: poll -> merge, else fallback
      int got = 0;
      if (lane == 0) {
        for (unsigned c2 = 0; c2 < (1u << 10); ++c2) {
          if (__hip_atomic_load(flag + p, __ATOMIC_RELAXED, __HIP_MEMORY_SCOPE_AGENT) != 0) {
            got = 1; break;
          }
          __builtin_amdgcn_s_sleep(2);
        }
        if (got)
          (void)__hip_atomic_load(flag + p, __ATOMIC_ACQUIRE, __HIP_MEMORY_SCOPE_AGENT);
      }
      got = __shfl(got, 0);
      if (got) {
        const float* pa = pacc + (size_t)p * 1024;
        float pm2 = pml[2 * p], pl2 = pml[2 * p + 1];
        float M = fmaxf(m, pm2);
        float e1 = __expf(m - M), e2 = __expf(pm2 - M);
#pragma unroll
        for (int j = 0; j < 16; ++j)
          acc[j] = acc[j] * e1 + pa[lane * 16 + j] * e2;
        l = l * e1 + pl2 * e2;
        m = M;
      } else {
        for (int s = len2; s < len; ++s) process(s);   // correct fallback
      }
      const float inv = 1.f / l;
#pragma unroll
      for (int j4 = 0; j4 < 4; ++j4) {
        ushort4 o;
        o.x = f2bf(acc[j4 * 4] * inv);
        o.y = f2bf(acc[j4 * 4 + 1] * inv);
        o.z = f2bf(acc[j4 * 4 + 2] * inv);
        o.w = f2bf(acc[j4 * 4 + 3] * inv);
        *(ushort4*)(wwbf + p * H_ + lane * 16 + j4 * 4) = o;
      }
    }
  }
}

// ---------------------------------------------------------------- converts (+compact)
__global__ __launch_bounds__(256) void convert_all(
    const float* __restrict__ W_ih, const float* __restrict__ W_hh,
    const float* __restrict__ W_in, const float* __restrict__ W_out,
    const float* __restrict__ trg_emb, const float* __restrict__ ctx,
    const float* __restrict__ b_ih, const float* __restrict__ b_hh,
    const float* __restrict__ h0, const float* __restrict__ c0,
    const int* __restrict__ src_len,
    u16* __restrict__ wWih, u16* __restrict__ wWhh, u16* __restrict__ wWin,
    u16* __restrict__ wWout, u16* __restrict__ wemb,
    float* __restrict__ wbsum, u16* __restrict__ wh0, u16* __restrict__ whtbf,
    float* __restrict__ wc, int* __restrict__ woffs, u16* __restrict__ ctxc) {
  __shared__ int tmp[256];
  const int bid = blockIdx.x;
  const int tid = threadIdx.x;
  const int gtid = bid * 256 + tid;
  const int GSZ = 1024 * 256;
  for (int i = gtid; i < 1572864; i += GSZ) {     // W_ih gi (4096x1536)
    const int r = i / 384, c4 = i - r * 384;
    const int rp = ((r & 1023) << 2) + (r >> 10);
    ((ushort4*)wWih)[(size_t)rp * 384 + c4] = cvt4bf(((const float4*)W_ih)[i]);
  }
  for (int i = gtid; i < 1048576; i += GSZ) {     // W_hh gi (4096x1024)
    const int r = i >> 8, c4 = i & 255;
    const int rp = ((r & 1023) << 2) + (r >> 10);
    ((ushort4*)wWhh)[(size_t)rp * 256 + c4] = cvt4bf(((const float4*)W_hh)[i]);
  }
  for (int i = gtid; i < 262144; i += GSZ)        // W_in (1024x1024)
    ((ushort4*)wWin)[i] = cvt4bf(((const float4*)W_in)[i]);
  for (int i = gtid; i < 524288; i += GSZ)        // W_out (1024x2048)
    ((ushort4*)wWout)[i] = cvt4bf(((const float4*)W_out)[i]);
  for (int i = gtid; i < 524288; i += GSZ)        // emb (B,T,E)
    ((ushort4*)wemb)[i] = cvt4bf(((const float4*)trg_emb)[i]);
  if (gtid < 4096) {                              // bias (gi)
    const int cp = ((gtid & 1023) << 2) + (gtid >> 10);
    wbsum[cp] = b_ih[gtid] + b_hh[gtid];
  }
  for (int i = gtid; i < 262144; i += GSZ) {      // state init
    u16 hb = f2bf(h0[i]);
    wh0[i] = hb;
    whtbf[i] = hb;
    wc[i] = c0[i];
  }
  if (bid >= 768) {                               // ctx compaction (256 blocks)
    const int b = bid - 768;
    tmp[tid] = (tid < b) ? src_len[tid] : 0;
    __syncthreads();
    for (int o = 128; o > 0; o >>= 1) {
      if (tid < o) tmp[tid] += tmp[tid + o];
      __syncthreads();
    }
    const int off = tmp[0];
    if (tid == 0) woffs[b] = off;
    const int n4 = src_len[b] << 8;               // len*1024/4 vec4s
    const float4* s = (const float4*)(ctx + ((size_t)b << 19));
    ushort4* d = (ushort4*)(ctxc + ((size_t)off << 10));
    for (int i = tid; i < n4; i += 256) d[i] = cvt4bf(s[i]);
  }
}

// ---------------------------------------------------------------- host
extern "C" void kernel_launch(void* const* d_in, const int* in_sizes, int n_in,
                              void* d_out, int out_size, void* d_ws, size_t ws_size,
                              hipStream_t stream) {
  const float* trg_emb = (const float*)d_in[0];
  const float* h0      = (const float*)d_in[1];
  const float* c0      = (const float*)d_in[2];
  const float* ctx     = (const float*)d_in[3];
  const int*   src_len = (const int*)d_in[4];
  const float* W_ih    = (const float*)d_in[5];
  const float* W_hh    = (const float*)d_in[6];
  const float* b_ih    = (const float*)d_in[7];
  const float* b_hh    = (const float*)d_in[8];
  const float* W_in    = (const float*)d_in[9];
  const float* W_out   = (const float*)d_in[10];
  float* out = (float*)d_out;

  char* w = (char*)d_ws;
  size_t off = 0;
  auto alloc = [&](size_t bytes) { char* p = w + off; off += bytes; return p; };
  u16*   wWih  = (u16*)  alloc(12582912);   // 4096x1536 bf16 (gi rows)
  u16*   wWhh  = (u16*)  alloc(8388608);    // 4096x1024 bf16 (gi rows)
  u16*   wWin  = (u16*)  alloc(2097152);    // 1024x1024
  u16*   wWout = (u16*)  alloc(4194304);    // 1024x2048
  u16*   wemb  = (u16*)  alloc(4194304);    // (B,T,E) bf16
  float* wbsum = (float*)alloc(16384);
  float* wc    = (float*)alloc(1048576);
  u16*   wh0   = (u16*)  alloc(524288);     // h ping
  u16*   wh1   = (u16*)  alloc(524288);     // h pong
  u16*   whtbf = (u16*)  alloc(524288);
  u16*   wtgt  = (u16*)  alloc(524288);
  u16*   wwbf  = (u16*)  alloc(524288);
  int*   woffs = (int*)  alloc(1024);
  int*   wflag = (int*)  alloc(16384);      // 16 steps x 256 pair flags
  float* pacc  = (float*)alloc(1048576);    // 256 x 1024 partial acc
  float* pml   = (float*)alloc(2048);       // 256 x (m,l)
  u16*   wctxc = (u16*)  alloc(268435456);  // compacted ctx bf16 (worst case)
  (void)ws_size;

  hipMemsetAsync(wflag, 0, 16384, stream);
  convert_all<<<dim3(1024), dim3(256), 0, stream>>>(
      W_ih, W_hh, W_in, W_out, trg_emb, ctx, b_ih, b_hh, h0, c0, src_len,
      wWih, wWhh, wWin, wWout, wemb, wbsum, wh0, whtbf, wc, woffs, wctxc);

  Reg3 rz = { nullptr, 0, nullptr, 0, 0 };
  for (int t = 0; t < T_; ++t) {
    const u16* hcur = (t & 1) ? wh1 : wh0;
    u16* hnxt = (t & 1) ? wh0 : wh1;
    // gates = [emb_t | htilde | h] @ [W_ihE | W_ihH | W_hh]^T (+bias) -> LSTM
    Reg3 g0 = { wemb + (size_t)t * E_, T_ * E_, wWih,      E_ + H_, 8 };
    Reg3 g1 = { whtbf,                 H_,      wWih + E_, E_ + H_, 16 };
    Reg3 g2 = { hcur,                  H_,      wWhh,      H_,      16 };
    gemm_k<3><<<dim3(256), dim3(256), 0, stream>>>(
        g0, g1, g2, 4, nullptr, nullptr, wbsum, wc, hnxt,
        (t == T_ - 1) ? out + (size_t)B_ * T_ * H_ : nullptr, 0);
    // target = h @ W_in^T  (M=256, N=1024, K=1024)
    Reg3 i0 = { hnxt, H_, wWin, H_, 16 };
    gemm_k<1><<<dim3(64), dim3(256), 0, stream>>>(
        i0, rz, rz, 4, nullptr, wtgt, nullptr, nullptr, nullptr, nullptr, 0);
    // attn: paired half-rows, online softmax, pairwise flag merge
    attn_pair<<<dim3(512), dim3(512), 0, stream>>>(
        wtgt, wctxc, woffs, src_len, wwbf, pacc, pml, wflag + t * 256);
    // htilde = tanh([weighted | h] @ W_out^T) -> out[:,t,:] + feedback
    Reg3 o0 = { wwbf, H_, wWout,      2 * H_, 16 };
    Reg3 o1 = { hnxt, H_, wWout + H_, 2 * H_, 16 };
    gemm_k<2><<<dim3(64), dim3(256), 0, stream>>>(
        o0, o1, rz, 4, out, whtbf, nullptr, nullptr, nullptr, nullptr, t);
  }
}